// Round 21
// baseline (132.992 us; speedup 1.0000x reference)
//
#include <hip/hip_runtime.h>
#include <hip/hip_bf16.h>
#include <math.h>

typedef __attribute__((ext_vector_type(8))) __bf16 bf16x8;
typedef __attribute__((ext_vector_type(4))) float f32x4;

#define S_LEN 1024
#define D_MODEL 384
#define BATCH 32
#define N3 1152
#define KVB 32
#define NT (S_LEN / KVB)

#define MFMA16(a, b, c) __builtin_amdgcn_mfma_f32_16x16x32_bf16((a), (b), (c), 0, 0, 0)

static __device__ __forceinline__ ushort f2bf(float f) {
    __bf16 h = (__bf16)f;
    return __builtin_bit_cast(ushort, h);
}
static __device__ __forceinline__ float exp2a(float x) {
    float r; asm("v_exp_f32 %0, %1" : "=v"(r) : "v"(x)); return r;
}
static __device__ __forceinline__ uint cvtpk(float a, float b) {
    uint r; asm("v_cvt_pk_bf16_f32 %0, %1, %2" : "=v"(r) : "v"(a), "v"(b)); return r;
}

// ---------------- kernel 1: positional-encoding table, transposed peT[k][s] ----
// ACCURATE sinf/cosf (R16 lesson: __sinf loses ~1e-3 at args ~1000 -> fail).
__global__ void pe_kernel(float* peT) {
    int idx = blockIdx.x * 256 + threadIdx.x;      // 384*1024 total
    int k = idx >> 10, s = idx & 1023;
    float e = -(float)((k >> 1) * 2) * (logf(10000.0f) / (float)D_MODEL);
    float div = expf(e);
    float a = (float)s * div;
    peT[idx] = (k & 1) ? cosf(a) : sinf(a);
}

// ---------------- kernel 2: W [384][1152] f32 -> Wt [1152][384] bf16 ----------
__global__ void wt_kernel(const float* __restrict__ W, ushort* __restrict__ Wt) {
    __shared__ float tile[32][33];
    int n0 = blockIdx.x * 32, k0 = blockIdx.y * 32;
    int tx = threadIdx.x, ty = threadIdx.y;
#pragma unroll
    for (int r = 0; r < 4; ++r) {
        int kl = ty * 4 + r;
        tile[kl][tx] = W[(size_t)(k0 + kl) * N3 + n0 + tx];
    }
    __syncthreads();
#pragma unroll
    for (int r = 0; r < 4; ++r) {
        int nl = ty * 4 + r;
        Wt[(size_t)(n0 + nl) * D_MODEL + k0 + tx] = f2bf(tile[tx][nl]);
    }
}

// ---------------- kernel 3: astage v2b — vectorized, PE from table ------------
__global__ __launch_bounds__(256) void astage_kernel(const float* __restrict__ x,
                                                     const float* __restrict__ peT,
                                                     ushort* __restrict__ A) {
    __shared__ ushort Ld[64 * 68];
    int sb = blockIdx.x, kb = blockIdx.y, b = blockIdx.z;
    int s0 = sb * 64, k0 = kb * 64;
    int t = threadIdx.x, l = t & 63, w = t >> 6;
    int sg = l & 15;
    const float4* x4 = (const float4*)x;
    const float4* p4 = (const float4*)peT;
#pragma unroll
    for (int r = 0; r < 4; ++r) {
        int kl = w * 4 + (l >> 4) + r * 16;          // 0..63, unique per (w,l,r)
        int kg = k0 + kl;
        float4 v = x4[((size_t)(b * D_MODEL + kg) << 8) + sb * 16 + sg];
        float4 p = p4[((size_t)kg << 8) + sb * 16 + sg];
        ushort4 o;
        o.x = f2bf(v.x + p.x); o.y = f2bf(v.y + p.y);
        o.z = f2bf(v.z + p.z); o.w = f2bf(v.w + p.w);
        *reinterpret_cast<ushort4*>(&Ld[kl * 68 + sg * 4]) = o;
    }
    __syncthreads();
#pragma unroll
    for (int p = 0; p < 2; ++p) {
        int s_loc = (t >> 3) + p * 32;               // 0..63
        int kg = t & 7;                              // 8-k group
        ushort4 o0, o1;
        o0.x = Ld[(kg * 8 + 0) * 68 + s_loc]; o0.y = Ld[(kg * 8 + 1) * 68 + s_loc];
        o0.z = Ld[(kg * 8 + 2) * 68 + s_loc]; o0.w = Ld[(kg * 8 + 3) * 68 + s_loc];
        o1.x = Ld[(kg * 8 + 4) * 68 + s_loc]; o1.y = Ld[(kg * 8 + 5) * 68 + s_loc];
        o1.z = Ld[(kg * 8 + 6) * 68 + s_loc]; o1.w = Ld[(kg * 8 + 7) * 68 + s_loc];
        ushort* dst = A + (size_t)(b * S_LEN + s0 + s_loc) * D_MODEL + k0 + kg * 8;
        *reinterpret_cast<ushort4*>(dst) = o0;
        *reinterpret_cast<ushort4*>(dst + 4) = o1;
    }
}

// ---------------- kernel 4: qkv GEMM v6 — v5 (no spill) + vectorized Q/K epi -
// SINGLE LEVER vs R20: Q/K blocks compute acc^T = mfma(B,A); C/D mapping puts
// 4 consecutive n in one lane -> ushort4 stores (64 -> 16 store instrs/thread).
// V blocks keep original orientation. Register count unchanged -> no spill.
__global__ __launch_bounds__(768, 1) void qkv_gemm(const ushort* __restrict__ A,
                                                   const ushort* __restrict__ Wt,
                                                   const float* __restrict__ bias,
                                                   ushort* __restrict__ Qb,
                                                   ushort* __restrict__ Ktl,
                                                   ushort* __restrict__ Vtl) {
    __shared__ __align__(16) ushort As[2][128 * 32];   // 2 x 8 KB
    __shared__ __align__(16) ushort Bs[2][384 * 32];   // 2 x 24 KB
    int id = blockIdx.x;                  // 768 = 8 chunks * (3 n * 32 m)
    int g = id / 96, loc = id % 96;
    int nt_ = loc / 32, mt_ = loc % 32;
    int m0 = g * 4096 + mt_ * 128, n0 = nt_ * 384;
    int tid = threadIdx.x;
    int wave = tid >> 6, lane = tid & 63;
    int i16 = lane & 15, gq = lane >> 4;
    int wr = wave / 6, wc = wave % 6;     // wave tile 64m x 64n

    auto stage = [&](int ks, int bi) {
        int k0 = ks * 32;
#pragma unroll
        for (int j = 0; j < 3; ++j) {
            int c = wave * 3 + j;                    // 0..35; use 0..31
            if (c < 8) {
                int row = c * 16 + (lane >> 2);
                const ushort* ga = A + (size_t)(m0 + row) * D_MODEL + k0 + (lane & 3) * 8;
                __builtin_amdgcn_global_load_lds(
                    (const __attribute__((address_space(1))) uint32_t*)ga,
                    (__attribute__((address_space(3))) uint32_t*)((char*)&As[bi][0] + c * 1024), 16, 0, 0);
            } else if (c < 32) {
                int row = (c - 8) * 16 + (lane >> 2);
                const ushort* gb = Wt + (size_t)(n0 + row) * D_MODEL + k0 + (lane & 3) * 8;
                __builtin_amdgcn_global_load_lds(
                    (const __attribute__((address_space(1))) uint32_t*)gb,
                    (__attribute__((address_space(3))) uint32_t*)((char*)&Bs[bi][0] + (c - 8) * 1024), 16, 0, 0);
            }
        }
    };

    stage(0, 0);
    f32x4 acc[4][4] = {};
    int b = m0 >> 10;

    if (n0 < 2 * D_MODEL) {
        // ---------- swapped orientation (Q/K): lane row = n, col = m ---------
        for (int ks = 0; ks < 12; ++ks) {
            int bi = ks & 1;
            asm volatile("s_waitcnt vmcnt(0) lgkmcnt(0)" ::: "memory");
            __builtin_amdgcn_s_barrier();
            __builtin_amdgcn_sched_barrier(0);
            if (ks + 1 < 12) stage(ks + 1, bi ^ 1);
            bf16x8 af[4], bfr[4];
#pragma unroll
            for (int mt = 0; mt < 4; ++mt) {
                int row = wr * 64 + mt * 16 + i16;
                af[mt] = *reinterpret_cast<const bf16x8*>(&As[bi][row * 32 + gq * 8]);
            }
#pragma unroll
            for (int nt = 0; nt < 4; ++nt) {
                int row = wc * 64 + nt * 16 + i16;
                bfr[nt] = *reinterpret_cast<const bf16x8*>(&Bs[bi][row * 32 + gq * 8]);
            }
            __builtin_amdgcn_s_setprio(1);
#pragma unroll
            for (int mt = 0; mt < 4; ++mt)
#pragma unroll
                for (int nt = 0; nt < 4; ++nt)
                    acc[mt][nt] = MFMA16(bfr[nt], af[mt], acc[mt][nt]);
            __builtin_amdgcn_s_setprio(0);
        }
        if (n0 == 0) {
            // Q: lane holds 4 consecutive n at fixed m -> ushort4
#pragma unroll
            for (int nt = 0; nt < 4; ++nt) {
                int n = wc * 64 + nt * 16 + gq * 4;
                float4 bv = *reinterpret_cast<const float4*>(&bias[n]);
#pragma unroll
                for (int mt = 0; mt < 4; ++mt) {
                    int m = m0 + wr * 64 + mt * 16 + i16;
                    ushort4 o;
                    o.x = f2bf(acc[mt][nt][0] + bv.x);
                    o.y = f2bf(acc[mt][nt][1] + bv.y);
                    o.z = f2bf(acc[mt][nt][2] + bv.z);
                    o.w = f2bf(acc[mt][nt][3] + bv.w);
                    *reinterpret_cast<ushort4*>(&Qb[(size_t)m * D_MODEL + n]) = o;
                }
            }
        } else {
            // K panel: within = (k2&7)+r contiguous; slotk constant over r
#pragma unroll
            for (int nt = 0; nt < 4; ++nt) {
                int k2 = wc * 64 + nt * 16 + gq * 4;
                float4 bv = *reinterpret_cast<const float4*>(&bias[D_MODEL + k2]);
                int slotk = k2 >> 3, wib = k2 & 7;           // wib in {0,4}
#pragma unroll
                for (int mt = 0; mt < 4; ++mt) {
                    int m = m0 + wr * 64 + mt * 16 + i16;
                    int s = m & 1023;
                    int t = s >> 5, j = s & 31;
                    size_t idx = (size_t)(b * 32 + t) * 12288 + j * 384
                               + (((slotk ^ (j & 7)) << 3) + wib);
                    ushort4 o;
                    o.x = f2bf(acc[mt][nt][0] + bv.x);
                    o.y = f2bf(acc[mt][nt][1] + bv.y);
                    o.z = f2bf(acc[mt][nt][2] + bv.z);
                    o.w = f2bf(acc[mt][nt][3] + bv.w);
                    *reinterpret_cast<ushort4*>(&Ktl[idx]) = o;
                }
            }
        }
    } else {
        // ---------- original orientation (V): row = m, col = n ----------
        for (int ks = 0; ks < 12; ++ks) {
            int bi = ks & 1;
            asm volatile("s_waitcnt vmcnt(0) lgkmcnt(0)" ::: "memory");
            __builtin_amdgcn_s_barrier();
            __builtin_amdgcn_sched_barrier(0);
            if (ks + 1 < 12) stage(ks + 1, bi ^ 1);
            bf16x8 af[4], bfr[4];
#pragma unroll
            for (int mt = 0; mt < 4; ++mt) {
                int row = wr * 64 + mt * 16 + i16;
                af[mt] = *reinterpret_cast<const bf16x8*>(&As[bi][row * 32 + gq * 8]);
            }
#pragma unroll
            for (int nt = 0; nt < 4; ++nt) {
                int row = wc * 64 + nt * 16 + i16;
                bfr[nt] = *reinterpret_cast<const bf16x8*>(&Bs[bi][row * 32 + gq * 8]);
            }
            __builtin_amdgcn_s_setprio(1);
#pragma unroll
            for (int mt = 0; mt < 4; ++mt)
#pragma unroll
                for (int nt = 0; nt < 4; ++nt)
                    acc[mt][nt] = MFMA16(af[mt], bfr[nt], acc[mt][nt]);
            __builtin_amdgcn_s_setprio(0);
        }
        // V panel: 4 consecutive s per ushort4 (j%4==0)
#pragma unroll
        for (int nt = 0; nt < 4; ++nt) {
            int c = wc * 64 + nt * 16 + i16;
            float bv = bias[2 * D_MODEL + c];
            int cx = (c >> 1) & 3;
#pragma unroll
            for (int mt = 0; mt < 4; ++mt) {
                int m = m0 + wr * 64 + mt * 16 + gq * 4;
                int s = m & 1023;
                int t = s >> 5, j = s & 31;       // j % 4 == 0
                size_t idx = (size_t)(b * 32 + t) * 12288 + c * 32
                           + ((((j >> 3) ^ cx) << 3) + (j & 7));
                ushort4 p4;
                p4.x = f2bf(acc[mt][nt][0] + bv);
                p4.y = f2bf(acc[mt][nt][1] + bv);
                p4.z = f2bf(acc[mt][nt][2] + bv);
                p4.w = f2bf(acc[mt][nt][3] + bv);
                *reinterpret_cast<ushort4*>(&Vtl[idx]) = p4;
            }
        }
    }
}

// ---------------- kernel 5: flash attention v13 (banked) ---------------------
// 256 blocks (1/CU), 768 threads = 12 waves -> 3 waves/SIMD (1 QK + 2 PV).
// Measured 63.7-64.2 us, MfmaUtil ~32, VGPR 84 (no spill).
__global__ __launch_bounds__(768, 1) void attn_kernel(const ushort* __restrict__ Qb,
                                                      const ushort* __restrict__ Ktl,
                                                      const ushort* __restrict__ Vtl,
                                                      float* __restrict__ out) {
    __shared__ __align__(16) char smem[114688];
    int id = blockIdx.x;                               // 256 = 8 qt * 4 slot * 8 xcd
    int xcd = id & 7, slot = (id >> 3) & 3, qt = id >> 5;
    int b = slot * 8 + xcd;
    int q0blk = qt * 128;
    int tid = threadIdx.x;
    int wave = tid >> 6, lane = tid & 63;
    int i16 = lane & 15, gq = lane >> 4;
    const float sl2e = 0.05103103630798287f * 1.4426950408889634f;

    auto stage_K = [&](int tt, int bi) {
        const ushort* pan = Ktl + (size_t)(b * 32 + tt) * 12288;
        char* dst = smem + bi * 24576;
#pragma unroll
        for (int r = 0; r < 2; ++r) {
            int ii = wave * 2 + r;
            const ushort* ga = pan + ii * 512 + lane * 8;
            __builtin_amdgcn_global_load_lds(
                (const __attribute__((address_space(1))) uint32_t*)ga,
                (__attribute__((address_space(3))) uint32_t*)(dst + ii * 1024), 16, 0, 0);
        }
    };
    auto stage_V = [&](int tt, int bi) {
        const ushort* pan = Vtl + (size_t)(b * 32 + tt) * 12288;
        char* dst = smem + 49152 + bi * 24576;
#pragma unroll
        for (int r = 0; r < 2; ++r) {
            int ii = wave * 2 + r;
            const ushort* ga = pan + ii * 512 + lane * 8;
            __builtin_amdgcn_global_load_lds(
                (const __attribute__((address_space(1))) uint32_t*)ga,
                (__attribute__((address_space(3))) uint32_t*)(dst + ii * 1024), 16, 0, 0);
        }
    };

    stage_K(0, 0);
    asm volatile("s_waitcnt vmcnt(0)" ::: "memory");
    __syncthreads();

    if (wave < 4) {
        int qg = wave;
        bf16x8 qf[12][2];
        const ushort* Q0 = Qb + (size_t)(b * S_LEN + q0blk + qg * 32 + i16) * D_MODEL;
        const ushort* Q1 = Q0 + (size_t)16 * D_MODEL;
#pragma unroll
        for (int kt = 0; kt < 12; ++kt) {
            qf[kt][0] = *reinterpret_cast<const bf16x8*>(Q0 + kt * 32 + gq * 8);
            qf[kt][1] = *reinterpret_cast<const bf16x8*>(Q1 + kt * 32 + gq * 8);
        }
        float lsum0 = 0.f, lsum1 = 0.f;
        int jc0 = gq >> 1, jc1 = 2 + (gq >> 1);
        int q0 = qg * 32 + i16, q1 = qg * 32 + 16 + i16;

        auto qk_step = [&](int tt) {
            const char* Kb = smem + (tt & 1) * 24576;
            char* Pw = smem + 98304 + (tt & 1) * 8192;
            f32x4 s00 = {}, s01 = {}, s10 = {}, s11 = {};
            __builtin_amdgcn_s_setprio(1);
#pragma unroll
            for (int kt = 0; kt < 12; ++kt) {
                int kc = (kt * 64 + gq * 16) ^ ((i16 & 7) << 4);
                bf16x8 kf0 = *reinterpret_cast<const bf16x8*>(Kb + i16 * 768 + kc);
                bf16x8 kf1 = *reinterpret_cast<const bf16x8*>(Kb + (16 + i16) * 768 + kc);
                s00 = MFMA16(kf0, qf[kt][0], s00);
                s01 = MFMA16(kf0, qf[kt][1], s01);
                s10 = MFMA16(kf1, qf[kt][0], s10);
                s11 = MFMA16(kf1, qf[kt][1], s11);
            }
            __builtin_amdgcn_s_setprio(0);
            {
                float p0 = exp2a(s00[0] * sl2e), p1 = exp2a(s00[1] * sl2e);
                float p2 = exp2a(s00[2] * sl2e), p3 = exp2a(s00[3] * sl2e);
                lsum0 += (p0 + p1) + (p2 + p3);
                uint2 w; w.x = cvtpk(p0, p1); w.y = cvtpk(p2, p3);
                *reinterpret_cast<uint2*>(Pw + jc0 * 2048 + ((q0 * 16) ^ ((jc0 & 3) << 4)) + (gq & 1) * 8) = w;
            }
            {
                float p0 = exp2a(s01[0] * sl2e), p1 = exp2a(s01[1] * sl2e);
                float p2 = exp2a(s01[2] * sl2e), p3 = exp2a(s01[3] * sl2e);
                lsum1 += (p0 + p1) + (p2 + p3);
                uint2 w; w.x = cvtpk(p0, p1); w.y = cvtpk(p2, p3);
                *reinterpret_cast<uint2*>(Pw + jc0 * 2048 + ((q1 * 16) ^ ((jc0 & 3) << 4)) + (gq & 1) * 8) = w;
            }
            {
                float p0 = exp2a(s10[0] * sl2e), p1 = exp2a(s10[1] * sl2e);
                float p2 = exp2a(s10[2] * sl2e), p3 = exp2a(s10[3] * sl2e);
                lsum0 += (p0 + p1) + (p2 + p3);
                uint2 w; w.x = cvtpk(p0, p1); w.y = cvtpk(p2, p3);
                *reinterpret_cast<uint2*>(Pw + jc1 * 2048 + ((q0 * 16) ^ ((jc1 & 3) << 4)) + (gq & 1) * 8) = w;
            }
            {
                float p0 = exp2a(s11[0] * sl2e), p1 = exp2a(s11[1] * sl2e);
                float p2 = exp2a(s11[2] * sl2e), p3 = exp2a(s11[3] * sl2e);
                lsum1 += (p0 + p1) + (p2 + p3);
                uint2 w; w.x = cvtpk(p0, p1); w.y = cvtpk(p2, p3);
                *reinterpret_cast<uint2*>(Pw + jc1 * 2048 + ((q1 * 16) ^ ((jc1 & 3) << 4)) + (gq & 1) * 8) = w;
            }
        };

        qk_step(0);
        stage_K(1, 1);
        stage_V(0, 0);
        asm volatile("s_waitcnt lgkmcnt(0)" ::: "memory");
        __builtin_amdgcn_s_barrier();                  // B#1
        for (int t = 0; t < NT; ++t) {
            asm volatile("s_waitcnt vmcnt(0) lgkmcnt(0)" ::: "memory");
            __builtin_amdgcn_s_barrier();              // B#2+t
            __builtin_amdgcn_sched_barrier(0);
            if (t + 2 < NT) stage_K(t + 2, t & 1);
            if (t + 1 < NT) stage_V(t + 1, (t + 1) & 1);
            if (t + 1 < NT) qk_step(t + 1);
        }
        __syncthreads();                               // B#2+NT
        lsum0 += __shfl_xor(lsum0, 16); lsum0 += __shfl_xor(lsum0, 32);
        lsum1 += __shfl_xor(lsum1, 16); lsum1 += __shfl_xor(lsum1, 32);
        float* Lt = reinterpret_cast<float*>(smem + 98304);
        if (gq == 0) {
            Lt[qg * 32 + i16] = lsum0;
            Lt[qg * 32 + 16 + i16] = lsum1;
        }
        __syncthreads();                               // B#3+NT
    } else {
        int cs = wave - 4;                             // 0..7
        f32x4 oc[3][8] = {};
        stage_K(1, 1);
        stage_V(0, 0);
        asm volatile("s_waitcnt lgkmcnt(0)" ::: "memory");
        __builtin_amdgcn_s_barrier();                  // B#1
        for (int t = 0; t < NT; ++t) {
            asm volatile("s_waitcnt vmcnt(0) lgkmcnt(0)" ::: "memory");
            __builtin_amdgcn_s_barrier();              // B#2+t
            __builtin_amdgcn_sched_barrier(0);
            if (t + 2 < NT) stage_K(t + 2, t & 1);
            if (t + 1 < NT) stage_V(t + 1, (t + 1) & 1);
            const char* Vb = smem + 49152 + (t & 1) * 24576;
            const char* Pb = smem + 98304 + (t & 1) * 8192;
            bf16x8 pf[8];
#pragma unroll
            for (int qs = 0; qs < 8; ++qs) {
                int q = qs * 16 + i16;
                pf[qs] = *reinterpret_cast<const bf16x8*>(
                    Pb + gq * 2048 + ((q * 16) ^ ((gq & 3) << 4)));
            }
            __builtin_amdgcn_s_setprio(1);
#pragma unroll
            for (int ct = 0; ct < 3; ++ct) {
                int c = cs * 48 + ct * 16 + i16;
                bf16x8 vf = *reinterpret_cast<const bf16x8*>(
                    Vb + c * 64 + ((gq * 16) ^ (((i16 >> 1) & 3) << 4)));
                oc[ct][0] = MFMA16(vf, pf[0], oc[ct][0]);
                oc[ct][1] = MFMA16(vf, pf[1], oc[ct][1]);
                oc[ct][2] = MFMA16(vf, pf[2], oc[ct][2]);
                oc[ct][3] = MFMA16(vf, pf[3], oc[ct][3]);
                oc[ct][4] = MFMA16(vf, pf[4], oc[ct][4]);
                oc[ct][5] = MFMA16(vf, pf[5], oc[ct][5]);
                oc[ct][6] = MFMA16(vf, pf[6], oc[ct][6]);
                oc[ct][7] = MFMA16(vf, pf[7], oc[ct][7]);
            }
            __builtin_amdgcn_s_setprio(0);
        }
        __syncthreads();                               // B#2+NT
        __syncthreads();                               // B#3+NT (Ltab now valid)
        const float* Lt = reinterpret_cast<const float*>(smem + 98304);
        float* ob = out + (size_t)b * D_MODEL * S_LEN + q0blk;
#pragma unroll
        for (int qs = 0; qs < 8; ++qs) {
            float inv = 1.0f / Lt[qs * 16 + i16];
#pragma unroll
            for (int ct = 0; ct < 3; ++ct)
#pragma unroll
                for (int r = 0; r < 4; ++r) {
                    int c = cs * 48 + ct * 16 + gq * 4 + r;
                    ob[(size_t)c * S_LEN + qs * 16 + i16] = oc[ct][qs][r] * inv;
                }
        }
    }
}

extern "C" void kernel_launch(void* const* d_in, const int* in_sizes, int n_in,
                              void* d_out, int out_size, void* d_ws, size_t ws_size,
                              hipStream_t stream) {
    const float* x    = (const float*)d_in[0];
    const float* W    = (const float*)d_in[1];
    const float* bias = (const float*)d_in[2];
    float* out = (float*)d_out;

    char* ws = (char*)d_ws;
    ushort* A_bf = (ushort*)(ws);                // 25,165,824
    ushort* Wt   = (ushort*)(ws + 25165824);     //    884,736
    float*  peT  = (float*)(ws + 26050560);      //  1,572,864
    ushort* Qb   = (ushort*)(ws + 27623424);     // 25,165,824
    ushort* Ktl  = (ushort*)(ws + 52789248);     // 25,165,824
    ushort* Vtl  = (ushort*)(ws + 77955072);     // 25,165,824  (total 103,120,896)

    pe_kernel<<<1536, 256, 0, stream>>>(peT);
    wt_kernel<<<dim3(36, 12), dim3(32, 8), 0, stream>>>(W, Wt);
    astage_kernel<<<dim3(16, 6, 32), 256, 0, stream>>>(x, peT, A_bf);
    qkv_gemm<<<768, 768, 0, stream>>>(A_bf, Wt, bias, Qb, Ktl, Vtl);
    attn_kernel<<<256, 768, 0, stream>>>(Qb, Ktl, Vtl, out);
}

// Round 22
// 128.199 us; speedup vs baseline: 1.0374x; 1.0374x over previous
//
#include <hip/hip_runtime.h>
#include <hip/hip_bf16.h>
#include <math.h>

typedef __attribute__((ext_vector_type(8))) __bf16 bf16x8;
typedef __attribute__((ext_vector_type(4))) float f32x4;

#define S_LEN 1024
#define D_MODEL 384
#define BATCH 32
#define N3 1152
#define KVB 32
#define NT (S_LEN / KVB)

#define MFMA16(a, b, c) __builtin_amdgcn_mfma_f32_16x16x32_bf16((a), (b), (c), 0, 0, 0)

static __device__ __forceinline__ ushort f2bf(float f) {
    __bf16 h = (__bf16)f;
    return __builtin_bit_cast(ushort, h);
}
static __device__ __forceinline__ float exp2a(float x) {
    float r; asm("v_exp_f32 %0, %1" : "=v"(r) : "v"(x)); return r;
}
static __device__ __forceinline__ uint cvtpk(float a, float b) {
    uint r; asm("v_cvt_pk_bf16_f32 %0, %1, %2" : "=v"(r) : "v"(a), "v"(b)); return r;
}

// ---------------- kernel 1: positional-encoding table, transposed peT[k][s] ----
// ACCURATE sinf/cosf (R16 lesson: __sinf loses ~1e-3 at args ~1000 -> fail).
__global__ void pe_kernel(float* peT) {
    int idx = blockIdx.x * 256 + threadIdx.x;      // 384*1024 total
    int k = idx >> 10, s = idx & 1023;
    float e = -(float)((k >> 1) * 2) * (logf(10000.0f) / (float)D_MODEL);
    float div = expf(e);
    float a = (float)s * div;
    peT[idx] = (k & 1) ? cosf(a) : sinf(a);
}

// ---------------- kernel 2: W [384][1152] f32 -> Wt [1152][384] bf16 ----------
__global__ void wt_kernel(const float* __restrict__ W, ushort* __restrict__ Wt) {
    __shared__ float tile[32][33];
    int n0 = blockIdx.x * 32, k0 = blockIdx.y * 32;
    int tx = threadIdx.x, ty = threadIdx.y;
#pragma unroll
    for (int r = 0; r < 4; ++r) {
        int kl = ty * 4 + r;
        tile[kl][tx] = W[(size_t)(k0 + kl) * N3 + n0 + tx];
    }
    __syncthreads();
#pragma unroll
    for (int r = 0; r < 4; ++r) {
        int nl = ty * 4 + r;
        Wt[(size_t)(n0 + nl) * D_MODEL + k0 + tx] = f2bf(tile[tx][nl]);
    }
}

// ---------------- kernel 3: astage v2b — vectorized, PE from table ------------
__global__ __launch_bounds__(256) void astage_kernel(const float* __restrict__ x,
                                                     const float* __restrict__ peT,
                                                     ushort* __restrict__ A) {
    __shared__ ushort Ld[64 * 68];
    int sb = blockIdx.x, kb = blockIdx.y, b = blockIdx.z;
    int s0 = sb * 64, k0 = kb * 64;
    int t = threadIdx.x, l = t & 63, w = t >> 6;
    int sg = l & 15;
    const float4* x4 = (const float4*)x;
    const float4* p4 = (const float4*)peT;
#pragma unroll
    for (int r = 0; r < 4; ++r) {
        int kl = w * 4 + (l >> 4) + r * 16;          // 0..63, unique per (w,l,r)
        int kg = k0 + kl;
        float4 v = x4[((size_t)(b * D_MODEL + kg) << 8) + sb * 16 + sg];
        float4 p = p4[((size_t)kg << 8) + sb * 16 + sg];
        ushort4 o;
        o.x = f2bf(v.x + p.x); o.y = f2bf(v.y + p.y);
        o.z = f2bf(v.z + p.z); o.w = f2bf(v.w + p.w);
        *reinterpret_cast<ushort4*>(&Ld[kl * 68 + sg * 4]) = o;
    }
    __syncthreads();
#pragma unroll
    for (int p = 0; p < 2; ++p) {
        int s_loc = (t >> 3) + p * 32;               // 0..63
        int kg = t & 7;                              // 8-k group
        ushort4 o0, o1;
        o0.x = Ld[(kg * 8 + 0) * 68 + s_loc]; o0.y = Ld[(kg * 8 + 1) * 68 + s_loc];
        o0.z = Ld[(kg * 8 + 2) * 68 + s_loc]; o0.w = Ld[(kg * 8 + 3) * 68 + s_loc];
        o1.x = Ld[(kg * 8 + 4) * 68 + s_loc]; o1.y = Ld[(kg * 8 + 5) * 68 + s_loc];
        o1.z = Ld[(kg * 8 + 6) * 68 + s_loc]; o1.w = Ld[(kg * 8 + 7) * 68 + s_loc];
        ushort* dst = A + (size_t)(b * S_LEN + s0 + s_loc) * D_MODEL + k0 + kg * 8;
        *reinterpret_cast<ushort4*>(dst) = o0;
        *reinterpret_cast<ushort4*>(dst + 4) = o1;
    }
}

// ---------------- kernel 4: qkv GEMM v5 — BM=128 x BN=384, 12 waves, NO SPILL
// (R20 exact: best measured config. R21's swapped Q/K epilogue regressed +4.6us
// and was reverted. acc 64 + frags 32 ~ 115 VGPR at launch_bounds(768,1).)
__global__ __launch_bounds__(768, 1) void qkv_gemm(const ushort* __restrict__ A,
                                                   const ushort* __restrict__ Wt,
                                                   const float* __restrict__ bias,
                                                   ushort* __restrict__ Qb,
                                                   ushort* __restrict__ Ktl,
                                                   ushort* __restrict__ Vtl) {
    __shared__ __align__(16) ushort As[2][128 * 32];   // 2 x 8 KB
    __shared__ __align__(16) ushort Bs[2][384 * 32];   // 2 x 24 KB
    int id = blockIdx.x;                  // 768 = 8 chunks * (3 n * 32 m)
    int g = id / 96, loc = id % 96;
    int nt_ = loc / 32, mt_ = loc % 32;
    int m0 = g * 4096 + mt_ * 128, n0 = nt_ * 384;
    int tid = threadIdx.x;
    int wave = tid >> 6, lane = tid & 63;
    int i16 = lane & 15, gq = lane >> 4;
    int wr = wave / 6, wc = wave % 6;     // wave tile 64m x 64n

    auto stage = [&](int ks, int bi) {
        int k0 = ks * 32;
#pragma unroll
        for (int j = 0; j < 3; ++j) {
            int c = wave * 3 + j;                    // 0..35; use 0..31
            if (c < 8) {
                int row = c * 16 + (lane >> 2);
                const ushort* ga = A + (size_t)(m0 + row) * D_MODEL + k0 + (lane & 3) * 8;
                __builtin_amdgcn_global_load_lds(
                    (const __attribute__((address_space(1))) uint32_t*)ga,
                    (__attribute__((address_space(3))) uint32_t*)((char*)&As[bi][0] + c * 1024), 16, 0, 0);
            } else if (c < 32) {
                int row = (c - 8) * 16 + (lane >> 2);
                const ushort* gb = Wt + (size_t)(n0 + row) * D_MODEL + k0 + (lane & 3) * 8;
                __builtin_amdgcn_global_load_lds(
                    (const __attribute__((address_space(1))) uint32_t*)gb,
                    (__attribute__((address_space(3))) uint32_t*)((char*)&Bs[bi][0] + (c - 8) * 1024), 16, 0, 0);
            }
        }
    };

    stage(0, 0);
    f32x4 acc[4][4] = {};
    for (int ks = 0; ks < 12; ++ks) {
        int bi = ks & 1;
        asm volatile("s_waitcnt vmcnt(0) lgkmcnt(0)" ::: "memory");
        __builtin_amdgcn_s_barrier();
        __builtin_amdgcn_sched_barrier(0);
        if (ks + 1 < 12) stage(ks + 1, bi ^ 1);
        bf16x8 af[4], bfr[4];
#pragma unroll
        for (int mt = 0; mt < 4; ++mt) {
            int row = wr * 64 + mt * 16 + i16;
            af[mt] = *reinterpret_cast<const bf16x8*>(&As[bi][row * 32 + gq * 8]);
        }
#pragma unroll
        for (int nt = 0; nt < 4; ++nt) {
            int row = wc * 64 + nt * 16 + i16;
            bfr[nt] = *reinterpret_cast<const bf16x8*>(&Bs[bi][row * 32 + gq * 8]);
        }
        __builtin_amdgcn_s_setprio(1);
#pragma unroll
        for (int mt = 0; mt < 4; ++mt)
#pragma unroll
            for (int nt = 0; nt < 4; ++nt)
                acc[mt][nt] = MFMA16(af[mt], bfr[nt], acc[mt][nt]);
        __builtin_amdgcn_s_setprio(0);
    }
    int b = m0 >> 10;
    if (n0 == 0) {
        // Q range: compact rows Qb[m][0..384)
#pragma unroll
        for (int nt = 0; nt < 4; ++nt) {
            int n = wc * 64 + nt * 16 + i16;
            float bv = bias[n];
#pragma unroll
            for (int mt = 0; mt < 4; ++mt)
#pragma unroll
                for (int r = 0; r < 4; ++r) {
                    int m = m0 + wr * 64 + mt * 16 + gq * 4 + r;
                    Qb[(size_t)m * D_MODEL + n] = f2bf(acc[mt][nt][r] + bv);
                }
        }
    } else if (n0 == D_MODEL) {
        // K range -> K_tiled panel, swizzle baked
#pragma unroll
        for (int nt = 0; nt < 4; ++nt) {
            int k2 = wc * 64 + nt * 16 + i16;
            float bv = bias[D_MODEL + k2];
            int slotk = k2 >> 3, within = k2 & 7;
#pragma unroll
            for (int mt = 0; mt < 4; ++mt)
#pragma unroll
                for (int r = 0; r < 4; ++r) {
                    int m = m0 + wr * 64 + mt * 16 + gq * 4 + r;
                    int s = m & 1023;
                    int t = s >> 5, j = s & 31;
                    size_t idx = (size_t)(b * 32 + t) * 12288 + j * 384
                               + (((slotk ^ (j & 7)) << 3) + within);
                    Ktl[idx] = f2bf(acc[mt][nt][r] + bv);
                }
        }
    } else {
        // V range -> V_tiled panel, swizzle baked (4 consecutive s per ushort4)
#pragma unroll
        for (int nt = 0; nt < 4; ++nt) {
            int c = wc * 64 + nt * 16 + i16;
            float bv = bias[2 * D_MODEL + c];
            int cx = (c >> 1) & 3;
#pragma unroll
            for (int mt = 0; mt < 4; ++mt) {
                int m = m0 + wr * 64 + mt * 16 + gq * 4;
                int s = m & 1023;
                int t = s >> 5, j = s & 31;       // j % 4 == 0
                size_t idx = (size_t)(b * 32 + t) * 12288 + c * 32
                           + ((((j >> 3) ^ cx) << 3) + (j & 7));
                ushort4 p4;
                p4.x = f2bf(acc[mt][nt][0] + bv);
                p4.y = f2bf(acc[mt][nt][1] + bv);
                p4.z = f2bf(acc[mt][nt][2] + bv);
                p4.w = f2bf(acc[mt][nt][3] + bv);
                *reinterpret_cast<ushort4*>(&Vtl[idx]) = p4;
            }
        }
    }
}

// ---------------- kernel 5: flash attention v13 (banked) ---------------------
// 256 blocks (1/CU), 768 threads = 12 waves -> 3 waves/SIMD (1 QK + 2 PV).
// Measured 63.7-64.2 us, MfmaUtil ~32, VGPR 84 (no spill).
__global__ __launch_bounds__(768, 1) void attn_kernel(const ushort* __restrict__ Qb,
                                                      const ushort* __restrict__ Ktl,
                                                      const ushort* __restrict__ Vtl,
                                                      float* __restrict__ out) {
    __shared__ __align__(16) char smem[114688];
    int id = blockIdx.x;                               // 256 = 8 qt * 4 slot * 8 xcd
    int xcd = id & 7, slot = (id >> 3) & 3, qt = id >> 5;
    int b = slot * 8 + xcd;
    int q0blk = qt * 128;
    int tid = threadIdx.x;
    int wave = tid >> 6, lane = tid & 63;
    int i16 = lane & 15, gq = lane >> 4;
    const float sl2e = 0.05103103630798287f * 1.4426950408889634f;

    auto stage_K = [&](int tt, int bi) {
        const ushort* pan = Ktl + (size_t)(b * 32 + tt) * 12288;
        char* dst = smem + bi * 24576;
#pragma unroll
        for (int r = 0; r < 2; ++r) {
            int ii = wave * 2 + r;
            const ushort* ga = pan + ii * 512 + lane * 8;
            __builtin_amdgcn_global_load_lds(
                (const __attribute__((address_space(1))) uint32_t*)ga,
                (__attribute__((address_space(3))) uint32_t*)(dst + ii * 1024), 16, 0, 0);
        }
    };
    auto stage_V = [&](int tt, int bi) {
        const ushort* pan = Vtl + (size_t)(b * 32 + tt) * 12288;
        char* dst = smem + 49152 + bi * 24576;
#pragma unroll
        for (int r = 0; r < 2; ++r) {
            int ii = wave * 2 + r;
            const ushort* ga = pan + ii * 512 + lane * 8;
            __builtin_amdgcn_global_load_lds(
                (const __attribute__((address_space(1))) uint32_t*)ga,
                (__attribute__((address_space(3))) uint32_t*)(dst + ii * 1024), 16, 0, 0);
        }
    };

    stage_K(0, 0);
    asm volatile("s_waitcnt vmcnt(0)" ::: "memory");
    __syncthreads();

    if (wave < 4) {
        int qg = wave;
        bf16x8 qf[12][2];
        const ushort* Q0 = Qb + (size_t)(b * S_LEN + q0blk + qg * 32 + i16) * D_MODEL;
        const ushort* Q1 = Q0 + (size_t)16 * D_MODEL;
#pragma unroll
        for (int kt = 0; kt < 12; ++kt) {
            qf[kt][0] = *reinterpret_cast<const bf16x8*>(Q0 + kt * 32 + gq * 8);
            qf[kt][1] = *reinterpret_cast<const bf16x8*>(Q1 + kt * 32 + gq * 8);
        }
        float lsum0 = 0.f, lsum1 = 0.f;
        int jc0 = gq >> 1, jc1 = 2 + (gq >> 1);
        int q0 = qg * 32 + i16, q1 = qg * 32 + 16 + i16;

        auto qk_step = [&](int tt) {
            const char* Kb = smem + (tt & 1) * 24576;
            char* Pw = smem + 98304 + (tt & 1) * 8192;
            f32x4 s00 = {}, s01 = {}, s10 = {}, s11 = {};
            __builtin_amdgcn_s_setprio(1);
#pragma unroll
            for (int kt = 0; kt < 12; ++kt) {
                int kc = (kt * 64 + gq * 16) ^ ((i16 & 7) << 4);
                bf16x8 kf0 = *reinterpret_cast<const bf16x8*>(Kb + i16 * 768 + kc);
                bf16x8 kf1 = *reinterpret_cast<const bf16x8*>(Kb + (16 + i16) * 768 + kc);
                s00 = MFMA16(kf0, qf[kt][0], s00);
                s01 = MFMA16(kf0, qf[kt][1], s01);
                s10 = MFMA16(kf1, qf[kt][0], s10);
                s11 = MFMA16(kf1, qf[kt][1], s11);
            }
            __builtin_amdgcn_s_setprio(0);
            {
                float p0 = exp2a(s00[0] * sl2e), p1 = exp2a(s00[1] * sl2e);
                float p2 = exp2a(s00[2] * sl2e), p3 = exp2a(s00[3] * sl2e);
                lsum0 += (p0 + p1) + (p2 + p3);
                uint2 w; w.x = cvtpk(p0, p1); w.y = cvtpk(p2, p3);
                *reinterpret_cast<uint2*>(Pw + jc0 * 2048 + ((q0 * 16) ^ ((jc0 & 3) << 4)) + (gq & 1) * 8) = w;
            }
            {
                float p0 = exp2a(s01[0] * sl2e), p1 = exp2a(s01[1] * sl2e);
                float p2 = exp2a(s01[2] * sl2e), p3 = exp2a(s01[3] * sl2e);
                lsum1 += (p0 + p1) + (p2 + p3);
                uint2 w; w.x = cvtpk(p0, p1); w.y = cvtpk(p2, p3);
                *reinterpret_cast<uint2*>(Pw + jc0 * 2048 + ((q1 * 16) ^ ((jc0 & 3) << 4)) + (gq & 1) * 8) = w;
            }
            {
                float p0 = exp2a(s10[0] * sl2e), p1 = exp2a(s10[1] * sl2e);
                float p2 = exp2a(s10[2] * sl2e), p3 = exp2a(s10[3] * sl2e);
                lsum0 += (p0 + p1) + (p2 + p3);
                uint2 w; w.x = cvtpk(p0, p1); w.y = cvtpk(p2, p3);
                *reinterpret_cast<uint2*>(Pw + jc1 * 2048 + ((q0 * 16) ^ ((jc1 & 3) << 4)) + (gq & 1) * 8) = w;
            }
            {
                float p0 = exp2a(s11[0] * sl2e), p1 = exp2a(s11[1] * sl2e);
                float p2 = exp2a(s11[2] * sl2e), p3 = exp2a(s11[3] * sl2e);
                lsum1 += (p0 + p1) + (p2 + p3);
                uint2 w; w.x = cvtpk(p0, p1); w.y = cvtpk(p2, p3);
                *reinterpret_cast<uint2*>(Pw + jc1 * 2048 + ((q1 * 16) ^ ((jc1 & 3) << 4)) + (gq & 1) * 8) = w;
            }
        };

        qk_step(0);
        stage_K(1, 1);
        stage_V(0, 0);
        asm volatile("s_waitcnt lgkmcnt(0)" ::: "memory");
        __builtin_amdgcn_s_barrier();                  // B#1
        for (int t = 0; t < NT; ++t) {
            asm volatile("s_waitcnt vmcnt(0) lgkmcnt(0)" ::: "memory");
            __builtin_amdgcn_s_barrier();              // B#2+t
            __builtin_amdgcn_sched_barrier(0);
            if (t + 2 < NT) stage_K(t + 2, t & 1);
            if (t + 1 < NT) stage_V(t + 1, (t + 1) & 1);
            if (t + 1 < NT) qk_step(t + 1);
        }
        __syncthreads();                               // B#2+NT
        lsum0 += __shfl_xor(lsum0, 16); lsum0 += __shfl_xor(lsum0, 32);
        lsum1 += __shfl_xor(lsum1, 16); lsum1 += __shfl_xor(lsum1, 32);
        float* Lt = reinterpret_cast<float*>(smem + 98304);
        if (gq == 0) {
            Lt[qg * 32 + i16] = lsum0;
            Lt[qg * 32 + 16 + i16] = lsum1;
        }
        __syncthreads();                               // B#3+NT
    } else {
        int cs = wave - 4;                             // 0..7
        f32x4 oc[3][8] = {};
        stage_K(1, 1);
        stage_V(0, 0);
        asm volatile("s_waitcnt lgkmcnt(0)" ::: "memory");
        __builtin_amdgcn_s_barrier();                  // B#1
        for (int t = 0; t < NT; ++t) {
            asm volatile("s_waitcnt vmcnt(0) lgkmcnt(0)" ::: "memory");
            __builtin_amdgcn_s_barrier();              // B#2+t
            __builtin_amdgcn_sched_barrier(0);
            if (t + 2 < NT) stage_K(t + 2, t & 1);
            if (t + 1 < NT) stage_V(t + 1, (t + 1) & 1);
            const char* Vb = smem + 49152 + (t & 1) * 24576;
            const char* Pb = smem + 98304 + (t & 1) * 8192;
            bf16x8 pf[8];
#pragma unroll
            for (int qs = 0; qs < 8; ++qs) {
                int q = qs * 16 + i16;
                pf[qs] = *reinterpret_cast<const bf16x8*>(
                    Pb + gq * 2048 + ((q * 16) ^ ((gq & 3) << 4)));
            }
            __builtin_amdgcn_s_setprio(1);
#pragma unroll
            for (int ct = 0; ct < 3; ++ct) {
                int c = cs * 48 + ct * 16 + i16;
                bf16x8 vf = *reinterpret_cast<const bf16x8*>(
                    Vb + c * 64 + ((gq * 16) ^ (((i16 >> 1) & 3) << 4)));
                oc[ct][0] = MFMA16(vf, pf[0], oc[ct][0]);
                oc[ct][1] = MFMA16(vf, pf[1], oc[ct][1]);
                oc[ct][2] = MFMA16(vf, pf[2], oc[ct][2]);
                oc[ct][3] = MFMA16(vf, pf[3], oc[ct][3]);
                oc[ct][4] = MFMA16(vf, pf[4], oc[ct][4]);
                oc[ct][5] = MFMA16(vf, pf[5], oc[ct][5]);
                oc[ct][6] = MFMA16(vf, pf[6], oc[ct][6]);
                oc[ct][7] = MFMA16(vf, pf[7], oc[ct][7]);
            }
            __builtin_amdgcn_s_setprio(0);
        }
        __syncthreads();                               // B#2+NT
        __syncthreads();                               // B#3+NT (Ltab now valid)
        const float* Lt = reinterpret_cast<const float*>(smem + 98304);
        float* ob = out + (size_t)b * D_MODEL * S_LEN + q0blk;
#pragma unroll
        for (int qs = 0; qs < 8; ++qs) {
            float inv = 1.0f / Lt[qs * 16 + i16];
#pragma unroll
            for (int ct = 0; ct < 3; ++ct)
#pragma unroll
                for (int r = 0; r < 4; ++r) {
                    int c = cs * 48 + ct * 16 + gq * 4 + r;
                    ob[(size_t)c * S_LEN + qs * 16 + i16] = oc[ct][qs][r] * inv;
                }
        }
    }
}

extern "C" void kernel_launch(void* const* d_in, const int* in_sizes, int n_in,
                              void* d_out, int out_size, void* d_ws, size_t ws_size,
                              hipStream_t stream) {
    const float* x    = (const float*)d_in[0];
    const float* W    = (const float*)d_in[1];
    const float* bias = (const float*)d_in[2];
    float* out = (float*)d_out;

    char* ws = (char*)d_ws;
    ushort* A_bf = (ushort*)(ws);                // 25,165,824
    ushort* Wt   = (ushort*)(ws + 25165824);     //    884,736
    float*  peT  = (float*)(ws + 26050560);      //  1,572,864
    ushort* Qb   = (ushort*)(ws + 27623424);     // 25,165,824
    ushort* Ktl  = (ushort*)(ws + 52789248);     // 25,165,824
    ushort* Vtl  = (ushort*)(ws + 77955072);     // 25,165,824  (total 103,120,896)

    pe_kernel<<<1536, 256, 0, stream>>>(peT);
    wt_kernel<<<dim3(36, 12), dim3(32, 8), 0, stream>>>(W, Wt);
    astage_kernel<<<dim3(16, 6, 32), 256, 0, stream>>>(x, peT, A_bf);
    qkv_gemm<<<768, 768, 0, stream>>>(A_bf, Wt, bias, Qb, Ktl, Vtl);
    attn_kernel<<<256, 768, 0, stream>>>(Qb, Ktl, Vtl, out);
}